// Round 3
// 1999.240 us; speedup vs baseline: 1.0890x; 1.0890x over previous
//
#include <hip/hip_runtime.h>
#include <math.h>

#define L_SEQ 2048
#define DM 1024
#define DFF 4096
#define NH 16
#define HD 64

typedef __bf16 bf16_t;
typedef __bf16 bf16x4 __attribute__((ext_vector_type(4)));
typedef __bf16 bf16x8 __attribute__((ext_vector_type(8)));
typedef float floatx4 __attribute__((ext_vector_type(4)));

__device__ __forceinline__ void gl_lds16(const void* g, void* l) {
    __builtin_amdgcn_global_load_lds((const __attribute__((address_space(1))) void*)g,
                                     (__attribute__((address_space(3))) void*)l, 16, 0, 0);
}

// ---------------- conv_in + relu + transpose: x[4,L] -> h[L, DM] fp32 ----------------
__global__ __launch_bounds__(256) void conv_in_kernel(const float* __restrict__ x,
                                                      const float* __restrict__ w,
                                                      const float* __restrict__ b,
                                                      float* __restrict__ h) {
    int gid = blockIdx.x * 256 + threadIdx.x;
    int d = gid & (DM - 1);
    int l = gid >> 10;
    float acc = b[d];
    const float* wd = w + d * 28;
#pragma unroll
    for (int c = 0; c < 4; ++c) {
#pragma unroll
        for (int k = 0; k < 7; ++k) {
            int t = l + k - 6;
            float xv = (t >= 0) ? x[c * L_SEQ + t] : 0.f;
            acc = fmaf(xv, wd[c * 7 + k], acc);
        }
    }
    h[(size_t)l * DM + d] = fmaxf(acc, 0.f);
}

// ---------------- RMSNorm fp32 in -> bf16 out ----------------
__global__ __launch_bounds__(256) void rmsnorm_kernel(const float* __restrict__ h,
                                                      const float* __restrict__ w,
                                                      const float* __restrict__ b,
                                                      bf16_t* __restrict__ out) {
    int l = blockIdx.x;
    int t = threadIdx.x;
    const float* row = h + (size_t)l * DM;
    float4 xv = *(const float4*)(row + t * 4);
    float ss = xv.x * xv.x + xv.y * xv.y + xv.z * xv.z + xv.w * xv.w;
#pragma unroll
    for (int off = 1; off < 64; off <<= 1) ss += __shfl_xor(ss, off, 64);
    __shared__ float red[4];
    if ((t & 63) == 0) red[t >> 6] = ss;
    __syncthreads();
    float tot = red[0] + red[1] + red[2] + red[3];
    float inv = rsqrtf(tot * (1.f / DM) + 1e-5f);
    float4 wv = *(const float4*)(w + t * 4);
    float4 bv = *(const float4*)(b + t * 4);
    bf16x4 ov;
    ov.x = (bf16_t)fmaf(xv.x * inv, wv.x, bv.x);
    ov.y = (bf16_t)fmaf(xv.y * inv, wv.y, bv.y);
    ov.z = (bf16_t)fmaf(xv.z * inv, wv.z, bv.z);
    ov.w = (bf16_t)fmaf(xv.w * inv, wv.w, bv.w);
    *(bf16x4*)(out + (size_t)l * DM + t * 4) = ov;
}

// ---------------- weight conversion fp32 -> bf16 ----------------
__global__ __launch_bounds__(256) void cvt_bf16(const float* __restrict__ in,
                                                bf16_t* __restrict__ out, int n4) {
    int i = blockIdx.x * 256 + threadIdx.x;
    if (i < n4) {
        float4 v = *(const float4*)(in + (size_t)i * 4);
        bf16x4 o = {(bf16_t)v.x, (bf16_t)v.y, (bf16_t)v.z, (bf16_t)v.w};
        *(bf16x4*)(out + (size_t)i * 4) = o;
    }
}

// wq/wk/wv [4][1024][1024] fp32 -> fused [4][3072][1024] bf16
__global__ __launch_bounds__(256) void cvt_qkvw(const float* __restrict__ wq,
                                                const float* __restrict__ wk,
                                                const float* __restrict__ wv,
                                                bf16_t* __restrict__ out) {
    int i = blockIdx.x * 256 + threadIdx.x;
    int layer = i / 786432;
    int rem = i - layer * 786432;
    int sel = rem / 262144;
    int idx = rem - sel * 262144;
    const float* src = (sel == 0 ? wq : sel == 1 ? wk : wv) + (size_t)layer * 1048576 + (size_t)idx * 4;
    float4 v = *(const float4*)src;
    bf16x4 o = {(bf16_t)v.x, (bf16_t)v.y, (bf16_t)v.z, (bf16_t)v.w};
    *(bf16x4*)(out + (size_t)i * 4) = o;
}

// ---------------- bf16 MFMA GEMM NT (m97 structure, kept for N=1024 GEMMs) ----------------
template <int TN, bool BIAS, bool RELU, bool RES, bool OUTBF>
__global__ __launch_bounds__(256) void gemm_bt(const bf16_t* __restrict__ A,
                                               const bf16_t* __restrict__ B,
                                               const float* __restrict__ bias,
                                               const float* __restrict__ res,
                                               void* __restrict__ Cout,
                                               int M, int N, int K) {
    constexpr int WMI = (TN == 128) ? 4 : 2;
    __shared__ alignas(16) bf16_t As[128 * 32];
    __shared__ alignas(16) bf16_t Bs[TN * 32];

    const int t = threadIdx.x;
    const int wave = t >> 6;
    const int lane = t & 63;
    const int quad = lane >> 4;
    const int l16 = lane & 15;
    const int m0 = blockIdx.y * 128;
    const int n0 = blockIdx.x * TN;

    const int wm = (TN == 128) ? (wave & 1) * 64 : wave * 32;
    const int wn = (TN == 128) ? (wave >> 1) * 64 : 0;

    floatx4 acc[WMI][4];
#pragma unroll
    for (int i = 0; i < WMI; ++i)
#pragma unroll
        for (int j = 0; j < 4; ++j) acc[i][j] = (floatx4)0.f;

    const int ldrow = t >> 2;
    const int ldk = (t & 3) * 8;
    const bf16_t* ga = A + (size_t)(m0 + ldrow) * K + ldk;
    const bf16_t* gb = B + (size_t)(n0 + ldrow) * K + ldk;
    char* lA = (char*)As + (size_t)wave * 1024;
    char* lB = (char*)Bs + (size_t)wave * 1024;

    for (int k0 = 0; k0 < K; k0 += 32) {
        gl_lds16(ga, lA);
        gl_lds16(ga + (size_t)64 * K, lA + 4096);
        gl_lds16(gb, lB);
        if (TN == 128) gl_lds16(gb + (size_t)64 * K, lB + 4096);
        ga += 32;
        gb += 32;
        __syncthreads();

        bf16x8 af[WMI], bfr[4];
#pragma unroll
        for (int i = 0; i < WMI; ++i)
            af[i] = *(const bf16x8*)((const char*)As + (size_t)(wm + i * 16 + l16) * 64 + quad * 16);
#pragma unroll
        for (int j = 0; j < 4; ++j)
            bfr[j] = *(const bf16x8*)((const char*)Bs + (size_t)(wn + j * 16 + l16) * 64 + quad * 16);
#pragma unroll
        for (int i = 0; i < WMI; ++i)
#pragma unroll
            for (int j = 0; j < 4; ++j)
                acc[i][j] = __builtin_amdgcn_mfma_f32_16x16x32_bf16(af[i], bfr[j], acc[i][j], 0, 0, 0);
        __syncthreads();
    }

#pragma unroll
    for (int i = 0; i < WMI; ++i) {
        const int m = m0 + wm + i * 16 + quad * 4;
#pragma unroll
        for (int j = 0; j < 4; ++j) {
            const int n = n0 + wn + j * 16 + l16;
            float bv = 0.f;
            if (BIAS) bv = bias[n];
#pragma unroll
            for (int r = 0; r < 4; ++r) {
                float v = acc[i][j][r] + bv;
                if (RELU) v = fmaxf(v, 0.f);
                if (RES) v += res[(size_t)(m + r) * N + n];
                if (OUTBF) ((bf16_t*)Cout)[(size_t)(m + r) * N + n] = (bf16_t)v;
                else ((float*)Cout)[(size_t)(m + r) * N + n] = v;
            }
        }
    }
}

// ---------------- pipelined bf16 MFMA GEMM NT: 128x256 tile, BK=32, 48KB LDS ----------------
// 8 waves (2M x 4N), per-wave 64x64. Double-buffered LDS (2 x 24KB, legal <64KB),
// 2-deep prefetch with counted vmcnt(3) at the tile boundary (never drains in steady state).
// Bank-swizzle: logical 16B-slot q of row r stored at phys slot q ^ ((r>>1)&3), applied as
// inverse-swizzled global source (global_load_lds writes linearly) + swizzled ds_read.
template <bool BIASRELU>
__global__ __launch_bounds__(512, 1) void gemm_pl(const bf16_t* __restrict__ A,
                                                  const bf16_t* __restrict__ B,
                                                  const float* __restrict__ bias,
                                                  bf16_t* __restrict__ C,
                                                  int M, int N, int K) {
    __shared__ alignas(16) char smem[49152];   // 2 x (A 8KB + B 16KB)
    const int t = threadIdx.x;
    const int w = t >> 6;
    const int lane = t & 63;
    const int quad = lane >> 4;
    const int l16 = lane & 15;
    const int bm = blockIdx.y * 128;
    const int bn = blockIdx.x * 256;
    const int wm = (w >> 2) * 64;   // 2 M-groups
    const int wn = (w & 3) * 64;    // 4 N-groups

    // ds_read offsets: row*64B + swizzled 16B slot. (row>>1)&3 == (l16>>1)&3 for all frags.
    const int swz = (quad ^ ((l16 >> 1) & 3)) << 4;
    int aoff[4], boff[4];
#pragma unroll
    for (int i = 0; i < 4; ++i) {
        aoff[i] = (wm + i * 16 + l16) * 64 + swz;
        boff[i] = 8192 + (wn + i * 16 + l16) * 64 + swz;
    }

    // staging: one round = 512 thr x 16B = 8KB = 128 rows of 64B; wave w covers 16 rows.
    const int srow = w * 16 + (lane >> 2);                       // row within round
    const int scl = (((lane & 3) ^ ((lane >> 3) & 3)) << 4);     // inverse-swizzled byte col
    const char* pA = (const char*)(A + (size_t)(bm + srow) * K) + scl;
    const char* pB = (const char*)(B + (size_t)(bn + srow) * K) + scl;
    const size_t r128 = (size_t)K * 256;       // 128 rows * K elems * 2B
    const int ldw = w * 1024;

    const int NT = K >> 5;                     // BK=32 -> 64B per row per tile

    floatx4 acc[4][4];
#pragma unroll
    for (int i = 0; i < 4; ++i)
#pragma unroll
        for (int j = 0; j < 4; ++j) acc[i][j] = (floatx4)0.f;

    // prologue: tile0 -> buf0, tile1 -> buf1 (3 loads each)
#pragma unroll
    for (int tt = 0; tt < 2; ++tt) {
        char* lb = smem + tt * 24576;
        gl_lds16(pA + (size_t)tt * 64, lb + ldw);
        gl_lds16(pB + (size_t)tt * 64, lb + 8192 + ldw);
        gl_lds16(pB + (size_t)tt * 64 + r128, lb + 8192 + ldw + 8192);
    }
    asm volatile("s_waitcnt vmcnt(3)" ::: "memory");  // tile0 landed; tile1 (3) in flight
    __builtin_amdgcn_s_barrier();

    for (int tile = 0; tile < NT; ++tile) {
        char* cb = smem + (tile & 1) * 24576;
        const bool st = (tile + 2) < NT;
        const size_t gof = (size_t)(tile + 2) * 64;

        // read this tile's fragments into registers
        bf16x8 af[4], bfr[4];
#pragma unroll
        for (int i = 0; i < 4; ++i) af[i] = *(const bf16x8*)(cb + aoff[i]);
#pragma unroll
        for (int j = 0; j < 4; ++j) bfr[j] = *(const bf16x8*)(cb + boff[j]);
        asm volatile("s_waitcnt lgkmcnt(0)" ::: "memory");
        __builtin_amdgcn_sched_barrier(0);
        __builtin_amdgcn_s_barrier();          // all waves done reading cb -> safe to overwrite

        // stage tile+2 into cb (the buffer just consumed)
        if (st) {
            gl_lds16(pA + gof, cb + ldw);
            gl_lds16(pB + gof, cb + 8192 + ldw);
            gl_lds16(pB + gof + r128, cb + 8192 + ldw + 8192);
        }

        __builtin_amdgcn_s_setprio(1);
#pragma unroll
        for (int i = 0; i < 4; ++i)
#pragma unroll
            for (int j = 0; j < 4; ++j)
                acc[i][j] = __builtin_amdgcn_mfma_f32_16x16x32_bf16(af[i], bfr[j], acc[i][j], 0, 0, 0);
        __builtin_amdgcn_s_setprio(0);

        // boundary: tile+1 fully landed; tile+2's 3 loads stay in flight
        if (st) asm volatile("s_waitcnt vmcnt(3)" ::: "memory");
        else    asm volatile("s_waitcnt vmcnt(0)" ::: "memory");
        __builtin_amdgcn_s_barrier();
    }

    // epilogue
#pragma unroll
    for (int j = 0; j < 4; ++j) {
        const int n = bn + wn + j * 16 + l16;
        const float bv = BIASRELU ? bias[n] : 0.f;
#pragma unroll
        for (int i = 0; i < 4; ++i) {
            const int m = bm + wm + i * 16 + quad * 4;
#pragma unroll
            for (int r = 0; r < 4; ++r) {
                float v = acc[i][j][r] + bv;
                if (BIASRELU) v = fmaxf(v, 0.f);
                C[(size_t)(m + r) * N + n] = (bf16_t)v;
            }
        }
    }
}

// ---------------- RoPE in-place on fused bf16 qkv [L][3072] ----------------
__global__ __launch_bounds__(256) void rope_kernel(bf16_t* __restrict__ qkv) {
    int gid = blockIdx.x * 256 + threadIdx.x;  // L*NH*32
    int j = gid & 31;
    int hh = (gid >> 5) & 15;
    int l = gid >> 9;
    float freq = powf(10000.f, -(float)(2 * j) * (1.f / 64.f));
    float ang = (float)l * freq;
    float s = sinf(ang), c = cosf(ang);
    size_t base = (size_t)l * 3072 + hh * HD + j;
    float q1 = (float)qkv[base], q2 = (float)qkv[base + 32];
    qkv[base] = (bf16_t)(q1 * c - q2 * s);
    qkv[base + 32] = (bf16_t)(q2 * c + q1 * s);
    size_t kb = base + 1024;
    float k1 = (float)qkv[kb], k2 = (float)qkv[kb + 32];
    qkv[kb] = (bf16_t)(k1 * c - k2 * s);
    qkv[kb + 32] = (bf16_t)(k2 * c + k1 * s);
}

// ---------------- V transpose: qkvb v-part [token][h*64+d] -> vt[h][d][token] ----------------
__global__ __launch_bounds__(256) void v_transpose(const bf16_t* __restrict__ qkvb,
                                                   bf16_t* __restrict__ vt) {
    __shared__ bf16_t Ts[64 * 72];
    const int h = blockIdx.x;
    const int tt = blockIdx.y;
    const int t = threadIdx.x;
#pragma unroll
    for (int i = 0; i < 2; ++i) {
        int idx = t + i * 256;
        int row = idx >> 3, dg = idx & 7;
        *(bf16x8*)(Ts + row * 72 + dg * 8) =
            *(const bf16x8*)(qkvb + (size_t)(tt * 64 + row) * 3072 + 2048 + h * 64 + dg * 8);
    }
    __syncthreads();
#pragma unroll
    for (int i = 0; i < 2; ++i) {
        int idx = t + i * 256;
        int d = idx >> 3, tg = idx & 7;
        bf16x8 v;
#pragma unroll
        for (int s = 0; s < 8; ++s) v[s] = Ts[(tg * 8 + s) * 72 + d];
        *(bf16x8*)(vt + ((size_t)h * 64 + d) * 2048 + tt * 64 + tg * 8) = v;
    }
}

// ---------------- MFMA flash attention (bf16 in/out, fp32 softmax) ----------------
__global__ __launch_bounds__(256) void attn_mfma(const bf16_t* __restrict__ qkvb,
                                                 const bf16_t* __restrict__ vt,
                                                 bf16_t* __restrict__ o) {
    __shared__ alignas(16) bf16_t Qs[64 * 72];
    __shared__ alignas(16) bf16_t Ks[64 * 72];
    __shared__ alignas(16) bf16_t Vs[64 * 72];   // [dim][key]
    __shared__ alignas(16) bf16_t Ps[4][16 * 72];
    const int t = threadIdx.x;
    const int wave = t >> 6;
    const int lane = t & 63;
    const int quad = lane >> 4;
    const int l16 = lane & 15;
    const int h = blockIdx.x;
    const int y = blockIdx.y;
    const int qt = (y < 16) ? (31 - y) : (y - 16);   // heavy/light pairing per CU
    const int l0 = qt * 64;

#pragma unroll
    for (int i = 0; i < 2; ++i) {
        int idx = t + i * 256;
        int row = idx >> 3, dg = idx & 7;
        *(bf16x8*)(Qs + row * 72 + dg * 8) =
            *(const bf16x8*)(qkvb + (size_t)(l0 + row) * 3072 + h * HD + dg * 8);
    }

    float m_r[4], l_r[4];
    floatx4 acc_o[4];
#pragma unroll
    for (int r = 0; r < 4; ++r) { m_r[r] = -1e30f; l_r[r] = 0.f; }
#pragma unroll
    for (int n = 0; n < 4; ++n) acc_o[n] = (floatx4)0.f;

    for (int jt = 0; jt <= qt; ++jt) {
        const int j0 = jt * 64;
        __syncthreads();
#pragma unroll
        for (int i = 0; i < 2; ++i) {
            int idx = t + i * 256;
            int row = idx >> 3, dg = idx & 7;
            *(bf16x8*)(Ks + row * 72 + dg * 8) =
                *(const bf16x8*)(qkvb + (size_t)(j0 + row) * 3072 + 1024 + h * HD + dg * 8);
            *(bf16x8*)(Vs + row * 72 + dg * 8) =
                *(const bf16x8*)(vt + ((size_t)h * HD + row) * 2048 + j0 + dg * 8);
        }
        __syncthreads();

        // S = Q K^T : wave's 16 q-rows x 64 keys
        bf16x8 aq0 = *(const bf16x8*)(Qs + (wave * 16 + l16) * 72 + quad * 8);
        bf16x8 aq1 = *(const bf16x8*)(Qs + (wave * 16 + l16) * 72 + 32 + quad * 8);
        floatx4 sacc[4];
#pragma unroll
        for (int j = 0; j < 4; ++j) {
            bf16x8 bk0 = *(const bf16x8*)(Ks + (j * 16 + l16) * 72 + quad * 8);
            bf16x8 bk1 = *(const bf16x8*)(Ks + (j * 16 + l16) * 72 + 32 + quad * 8);
            floatx4 s = (floatx4)0.f;
            s = __builtin_amdgcn_mfma_f32_16x16x32_bf16(aq0, bk0, s, 0, 0, 0);
            s = __builtin_amdgcn_mfma_f32_16x16x32_bf16(aq1, bk1, s, 0, 0, 0);
            sacc[j] = s;
        }

        const bool diag = (jt == qt);
        float mt[4];
#pragma unroll
        for (int r = 0; r < 4; ++r) mt[r] = -1e30f;
#pragma unroll
        for (int j = 0; j < 4; ++j)
#pragma unroll
            for (int r = 0; r < 4; ++r) {
                float sv = sacc[j][r] * 0.125f;
                if (diag && (j * 16 + l16) > (wave * 16 + quad * 4 + r)) sv = -1e30f;
                sacc[j][r] = sv;
                mt[r] = fmaxf(mt[r], sv);
            }
#pragma unroll
        for (int r = 0; r < 4; ++r) {
            mt[r] = fmaxf(mt[r], __shfl_xor(mt[r], 1, 64));
            mt[r] = fmaxf(mt[r], __shfl_xor(mt[r], 2, 64));
            mt[r] = fmaxf(mt[r], __shfl_xor(mt[r], 4, 64));
            mt[r] = fmaxf(mt[r], __shfl_xor(mt[r], 8, 64));
        }
        float alpha[4], rs[4];
#pragma unroll
        for (int r = 0; r < 4; ++r) {
            float mn = fmaxf(m_r[r], mt[r]);
            alpha[r] = __expf(m_r[r] - mn);
            m_r[r] = mn;
            rs[r] = 0.f;
        }
#pragma unroll
        for (int j = 0; j < 4; ++j)
#pragma unroll
            for (int r = 0; r < 4; ++r) {
                float p = __expf(sacc[j][r] - m_r[r]);
                sacc[j][r] = p;
                rs[r] += p;
            }
#pragma unroll
        for (int r = 0; r < 4; ++r) {
            rs[r] += __shfl_xor(rs[r], 1, 64);
            rs[r] += __shfl_xor(rs[r], 2, 64);
            rs[r] += __shfl_xor(rs[r], 4, 64);
            rs[r] += __shfl_xor(rs[r], 8, 64);
            l_r[r] = l_r[r] * alpha[r] + rs[r];
        }
#pragma unroll
        for (int n = 0; n < 4; ++n)
#pragma unroll
            for (int r = 0; r < 4; ++r) acc_o[n][r] *= alpha[r];

        bf16_t* pw = Ps[wave];
#pragma unroll
        for (int j = 0; j < 4; ++j)
#pragma unroll
            for (int r = 0; r < 4; ++r)
                pw[(quad * 4 + r) * 72 + j * 16 + l16] = (bf16_t)sacc[j][r];

        bf16x8 ap0 = *(const bf16x8*)(pw + l16 * 72 + quad * 8);
        bf16x8 ap1 = *(const bf16x8*)(pw + l16 * 72 + 32 + quad * 8);
#pragma unroll
        for (int n = 0; n < 4; ++n) {
            bf16x8 bv0 = *(const bf16x8*)(Vs + (n * 16 + l16) * 72 + quad * 8);
            bf16x8 bv1 = *(const bf16x8*)(Vs + (n * 16 + l16) * 72 + 32 + quad * 8);
            acc_o[n] = __builtin_amdgcn_mfma_f32_16x16x32_bf16(ap0, bv0, acc_o[n], 0, 0, 0);
            acc_o[n] = __builtin_amdgcn_mfma_f32_16x16x32_bf16(ap1, bv1, acc_o[n], 0, 0, 0);
        }
    }

#pragma unroll
    for (int r = 0; r < 4; ++r) {
        float inv = 1.f / l_r[r];
        int row = l0 + wave * 16 + quad * 4 + r;
#pragma unroll
        for (int n = 0; n < 4; ++n)
            o[(size_t)row * DM + h * HD + n * 16 + l16] = (bf16_t)(acc_o[n][r] * inv);
    }
}

// ---------------- conv_out: h[L,DM] fp32 -> out[4, L] ----------------
__global__ __launch_bounds__(256) void conv_out_kernel(const float* __restrict__ h,
                                                       const float* __restrict__ w,
                                                       const float* __restrict__ b,
                                                       float* __restrict__ out) {
    int c = blockIdx.x >> 11;
    int l = blockIdx.x & 2047;
    int t = threadIdx.x;
    float acc = 0.f;
    const float* wc = w + c * (DM * 7);
    for (int idx = t; idx < DM * 7; idx += 256) {
        int d = idx / 7;
        int kk = idx - d * 7;
        int tt = l + kk - 6;
        if (tt >= 0) acc = fmaf(h[(size_t)tt * DM + d], wc[idx], acc);
    }
#pragma unroll
    for (int off = 1; off < 64; off <<= 1) acc += __shfl_xor(acc, off, 64);
    __shared__ float red[4];
    if ((t & 63) == 0) red[t >> 6] = acc;
    __syncthreads();
    if (t == 0) out[blockIdx.x] = red[0] + red[1] + red[2] + red[3] + b[c];
}

extern "C" void kernel_launch(void* const* d_in, const int* in_sizes, int n_in,
                              void* d_out, int out_size, void* d_ws, size_t ws_size,
                              hipStream_t stream) {
    const float* x = (const float*)d_in[0];
    const float* conv_in_w = (const float*)d_in[1];
    const float* conv_in_b = (const float*)d_in[2];
    const float* ln1_w = (const float*)d_in[3];
    const float* ln1_b = (const float*)d_in[4];
    const float* wq = (const float*)d_in[5];
    const float* wk = (const float*)d_in[6];
    const float* wv = (const float*)d_in[7];
    const float* wo = (const float*)d_in[8];
    const float* ln2_w = (const float*)d_in[9];
    const float* ln2_b = (const float*)d_in[10];
    const float* w1 = (const float*)d_in[11];
    const float* b1 = (const float*)d_in[12];
    const float* w2 = (const float*)d_in[13];
    const float* b2 = (const float*)d_in[14];
    const float* w3 = (const float*)d_in[15];
    const float* b3 = (const float*)d_in[16];
    const float* conv_out_w = (const float*)d_in[17];
    const float* conv_out_b = (const float*)d_in[18];

    char* W = (char*)d_ws;
    float* h = (float*)(W);                                  // 8 MB
    bf16_t* qkvb = (bf16_t*)(W + (8ull << 20));              // 12 MB [2048][3072] bf16
    bf16_t* hn = (bf16_t*)(W + (20ull << 20));               // 4 MB
    bf16_t* ob = (bf16_t*)(W + (24ull << 20));               // 4 MB
    bf16_t* f1 = (bf16_t*)(W + (28ull << 20));               // 16 MB
    bf16_t* f2 = (bf16_t*)(W + (44ull << 20));               // 16 MB
    bf16_t* vtb = (bf16_t*)(W + (60ull << 20));              // 4 MB [16][64][2048] bf16
    bf16_t* qkvw = (bf16_t*)(W + (64ull << 20));             // 24 MB
    bf16_t* wob = (bf16_t*)(W + (88ull << 20));              // 8 MB
    bf16_t* w1b = (bf16_t*)(W + (96ull << 20));              // 32 MB
    bf16_t* w2b = (bf16_t*)(W + (128ull << 20));             // 128 MB
    bf16_t* w3b = (bf16_t*)(W + (256ull << 20));             // 32 MB (end 288 MB)

    cvt_qkvw<<<12288, 256, 0, stream>>>(wq, wk, wv, qkvw);
    cvt_bf16<<<4096, 256, 0, stream>>>(wo, wob, 1048576);
    cvt_bf16<<<16384, 256, 0, stream>>>(w1, w1b, 4194304);
    cvt_bf16<<<65536, 256, 0, stream>>>(w2, w2b, 16777216);
    cvt_bf16<<<16384, 256, 0, stream>>>(w3, w3b, 4194304);

    conv_in_kernel<<<(L_SEQ * DM) / 256, 256, 0, stream>>>(x, conv_in_w, conv_in_b, h);

    for (int layer = 0; layer < 4; ++layer) {
        const float* ln1w = ln1_w + layer * DM;
        const float* ln1b = ln1_b + layer * DM;
        const float* ln2w = ln2_w + layer * DM;
        const float* ln2b = ln2_b + layer * DM;
        const bf16_t* qkvw_l = qkvw + (size_t)layer * 3072 * 1024;
        const bf16_t* wob_l = wob + (size_t)layer * DM * DM;
        const bf16_t* w1b_l = w1b + (size_t)layer * DFF * DM;
        const bf16_t* w2b_l = w2b + (size_t)layer * DFF * DFF;
        const bf16_t* w3b_l = w3b + (size_t)layer * DM * DFF;
        const float* b1_l = b1 + (size_t)layer * DFF;
        const float* b2_l = b2 + (size_t)layer * DFF;
        const float* b3_l = b3 + (size_t)layer * DM;

        rmsnorm_kernel<<<L_SEQ, 256, 0, stream>>>(h, ln1w, ln1b, hn);
        gemm_pl<false><<<dim3(3072 / 256, L_SEQ / 128), 512, 0, stream>>>(
            hn, qkvw_l, nullptr, qkvb, L_SEQ, 3072, 1024);
        rope_kernel<<<(L_SEQ * NH * 32) / 256, 256, 0, stream>>>(qkvb);
        v_transpose<<<dim3(NH, L_SEQ / 64), 256, 0, stream>>>(qkvb, vtb);
        attn_mfma<<<dim3(NH, L_SEQ / 64), 256, 0, stream>>>(qkvb, vtb, ob);
        gemm_bt<64, false, false, true, false><<<dim3(DM / 64, L_SEQ / 128), 256, 0, stream>>>(
            ob, wob_l, nullptr, h, h, L_SEQ, DM, DM);
        rmsnorm_kernel<<<L_SEQ, 256, 0, stream>>>(h, ln2w, ln2b, hn);
        gemm_pl<true><<<dim3(DFF / 256, L_SEQ / 128), 512, 0, stream>>>(
            hn, w1b_l, b1_l, f1, L_SEQ, DFF, 1024);
        gemm_pl<true><<<dim3(DFF / 256, L_SEQ / 128), 512, 0, stream>>>(
            f1, w2b_l, b2_l, f2, L_SEQ, DFF, DFF);
        gemm_bt<64, true, false, true, false><<<dim3(DM / 64, L_SEQ / 128), 256, 0, stream>>>(
            f2, w3b_l, b3_l, h, h, L_SEQ, DM, DFF);
    }

    conv_out_kernel<<<4 * L_SEQ, 256, 0, stream>>>(h, conv_out_w, conv_out_b, (float*)d_out);
}

// Round 4
// 1978.830 us; speedup vs baseline: 1.1003x; 1.0103x over previous
//
#include <hip/hip_runtime.h>
#include <math.h>

#define L_SEQ 2048
#define DM 1024
#define DFF 4096
#define NH 16
#define HD 64

typedef __bf16 bf16_t;
typedef __bf16 bf16x4 __attribute__((ext_vector_type(4)));
typedef __bf16 bf16x8 __attribute__((ext_vector_type(8)));
typedef float floatx4 __attribute__((ext_vector_type(4)));

__device__ __forceinline__ void gl_lds16(const void* g, void* l) {
    __builtin_amdgcn_global_load_lds((const __attribute__((address_space(1))) void*)g,
                                     (__attribute__((address_space(3))) void*)l, 16, 0, 0);
}

// ---------------- conv_in + relu + transpose: x[4,L] -> h[L, DM] fp32 ----------------
__global__ __launch_bounds__(256) void conv_in_kernel(const float* __restrict__ x,
                                                      const float* __restrict__ w,
                                                      const float* __restrict__ b,
                                                      float* __restrict__ h) {
    int gid = blockIdx.x * 256 + threadIdx.x;
    int d = gid & (DM - 1);
    int l = gid >> 10;
    float acc = b[d];
    const float* wd = w + d * 28;
#pragma unroll
    for (int c = 0; c < 4; ++c) {
#pragma unroll
        for (int k = 0; k < 7; ++k) {
            int t = l + k - 6;
            float xv = (t >= 0) ? x[c * L_SEQ + t] : 0.f;
            acc = fmaf(xv, wd[c * 7 + k], acc);
        }
    }
    h[(size_t)l * DM + d] = fmaxf(acc, 0.f);
}

// ---------------- RMSNorm fp32 in -> bf16 out ----------------
__global__ __launch_bounds__(256) void rmsnorm_kernel(const float* __restrict__ h,
                                                      const float* __restrict__ w,
                                                      const float* __restrict__ b,
                                                      bf16_t* __restrict__ out) {
    int l = blockIdx.x;
    int t = threadIdx.x;
    const float* row = h + (size_t)l * DM;
    float4 xv = *(const float4*)(row + t * 4);
    float ss = xv.x * xv.x + xv.y * xv.y + xv.z * xv.z + xv.w * xv.w;
#pragma unroll
    for (int off = 1; off < 64; off <<= 1) ss += __shfl_xor(ss, off, 64);
    __shared__ float red[4];
    if ((t & 63) == 0) red[t >> 6] = ss;
    __syncthreads();
    float tot = red[0] + red[1] + red[2] + red[3];
    float inv = rsqrtf(tot * (1.f / DM) + 1e-5f);
    float4 wv = *(const float4*)(w + t * 4);
    float4 bv = *(const float4*)(b + t * 4);
    bf16x4 ov;
    ov.x = (bf16_t)fmaf(xv.x * inv, wv.x, bv.x);
    ov.y = (bf16_t)fmaf(xv.y * inv, wv.y, bv.y);
    ov.z = (bf16_t)fmaf(xv.z * inv, wv.z, bv.z);
    ov.w = (bf16_t)fmaf(xv.w * inv, wv.w, bv.w);
    *(bf16x4*)(out + (size_t)l * DM + t * 4) = ov;
}

// ---------------- weight conversion fp32 -> bf16 ----------------
__global__ __launch_bounds__(256) void cvt_bf16(const float* __restrict__ in,
                                                bf16_t* __restrict__ out, int n4) {
    int i = blockIdx.x * 256 + threadIdx.x;
    if (i < n4) {
        float4 v = *(const float4*)(in + (size_t)i * 4);
        bf16x4 o = {(bf16_t)v.x, (bf16_t)v.y, (bf16_t)v.z, (bf16_t)v.w};
        *(bf16x4*)(out + (size_t)i * 4) = o;
    }
}

// wq/wk/wv [4][1024][1024] fp32 -> fused [4][3072][1024] bf16
__global__ __launch_bounds__(256) void cvt_qkvw(const float* __restrict__ wq,
                                                const float* __restrict__ wk,
                                                const float* __restrict__ wv,
                                                bf16_t* __restrict__ out) {
    int i = blockIdx.x * 256 + threadIdx.x;
    int layer = i / 786432;
    int rem = i - layer * 786432;
    int sel = rem / 262144;
    int idx = rem - sel * 262144;
    const float* src = (sel == 0 ? wq : sel == 1 ? wk : wv) + (size_t)layer * 1048576 + (size_t)idx * 4;
    float4 v = *(const float4*)src;
    bf16x4 o = {(bf16_t)v.x, (bf16_t)v.y, (bf16_t)v.z, (bf16_t)v.w};
    *(bf16x4*)(out + (size_t)i * 4) = o;
}

// ---------------- bf16 MFMA GEMM NT (m97 structure, kept for N=1024 GEMMs) ----------------
template <int TN, bool BIAS, bool RELU, bool RES, bool OUTBF>
__global__ __launch_bounds__(256) void gemm_bt(const bf16_t* __restrict__ A,
                                               const bf16_t* __restrict__ B,
                                               const float* __restrict__ bias,
                                               const float* __restrict__ res,
                                               void* __restrict__ Cout,
                                               int M, int N, int K) {
    constexpr int WMI = (TN == 128) ? 4 : 2;
    __shared__ alignas(16) bf16_t As[128 * 32];
    __shared__ alignas(16) bf16_t Bs[TN * 32];

    const int t = threadIdx.x;
    const int wave = t >> 6;
    const int lane = t & 63;
    const int quad = lane >> 4;
    const int l16 = lane & 15;
    const int m0 = blockIdx.y * 128;
    const int n0 = blockIdx.x * TN;

    const int wm = (TN == 128) ? (wave & 1) * 64 : wave * 32;
    const int wn = (TN == 128) ? (wave >> 1) * 64 : 0;

    floatx4 acc[WMI][4];
#pragma unroll
    for (int i = 0; i < WMI; ++i)
#pragma unroll
        for (int j = 0; j < 4; ++j) acc[i][j] = (floatx4)0.f;

    const int ldrow = t >> 2;
    const int ldk = (t & 3) * 8;
    const bf16_t* ga = A + (size_t)(m0 + ldrow) * K + ldk;
    const bf16_t* gb = B + (size_t)(n0 + ldrow) * K + ldk;
    char* lA = (char*)As + (size_t)wave * 1024;
    char* lB = (char*)Bs + (size_t)wave * 1024;

    for (int k0 = 0; k0 < K; k0 += 32) {
        gl_lds16(ga, lA);
        gl_lds16(ga + (size_t)64 * K, lA + 4096);
        gl_lds16(gb, lB);
        if (TN == 128) gl_lds16(gb + (size_t)64 * K, lB + 4096);
        ga += 32;
        gb += 32;
        __syncthreads();

        bf16x8 af[WMI], bfr[4];
#pragma unroll
        for (int i = 0; i < WMI; ++i)
            af[i] = *(const bf16x8*)((const char*)As + (size_t)(wm + i * 16 + l16) * 64 + quad * 16);
#pragma unroll
        for (int j = 0; j < 4; ++j)
            bfr[j] = *(const bf16x8*)((const char*)Bs + (size_t)(wn + j * 16 + l16) * 64 + quad * 16);
#pragma unroll
        for (int i = 0; i < WMI; ++i)
#pragma unroll
            for (int j = 0; j < 4; ++j)
                acc[i][j] = __builtin_amdgcn_mfma_f32_16x16x32_bf16(af[i], bfr[j], acc[i][j], 0, 0, 0);
        __syncthreads();
    }

#pragma unroll
    for (int i = 0; i < WMI; ++i) {
        const int m = m0 + wm + i * 16 + quad * 4;
#pragma unroll
        for (int j = 0; j < 4; ++j) {
            const int n = n0 + wn + j * 16 + l16;
            float bv = 0.f;
            if (BIAS) bv = bias[n];
#pragma unroll
            for (int r = 0; r < 4; ++r) {
                float v = acc[i][j][r] + bv;
                if (RELU) v = fmaxf(v, 0.f);
                if (RES) v += res[(size_t)(m + r) * N + n];
                if (OUTBF) ((bf16_t*)Cout)[(size_t)(m + r) * N + n] = (bf16_t)v;
                else ((float*)Cout)[(size_t)(m + r) * N + n] = v;
            }
        }
    }
}

// ---------------- pipelined bf16 MFMA GEMM NT: 128x128 tile, BK=32, 32KB LDS ----------------
// 4 waves (2M x 2N), per-wave 64x64 (same per-wave shape as before: 8 ds_read : 16 MFMA).
// 2x smaller tile doubles the grid (W1/W2: 512 wgs = 2 blocks/CU) for TLP (m103: 128^2 > 128x256
// at the 2-barrier structure). Double-buffered LDS (2 x 16KB), 2-deep prefetch, counted vmcnt(4).
// Bank-swizzle identical to the verified round-3 scheme (64B rows, hash (row>>1)&3, rule 21).
template <bool BIASRELU>
__global__ __launch_bounds__(256, 2) void gemm_pl(const bf16_t* __restrict__ A,
                                                  const bf16_t* __restrict__ B,
                                                  const float* __restrict__ bias,
                                                  bf16_t* __restrict__ C,
                                                  int M, int N, int K) {
    __shared__ alignas(16) char smem[32768];   // 2 x (A 8KB + B 8KB)
    const int t = threadIdx.x;
    const int w = t >> 6;
    const int lane = t & 63;
    const int quad = lane >> 4;
    const int l16 = lane & 15;
    const int bm = blockIdx.y * 128;
    const int bn = blockIdx.x * 128;
    const int wm = (w >> 1) * 64;   // 2 M-groups
    const int wn = (w & 1) * 64;    // 2 N-groups

    // ds_read offsets: row*64B + swizzled 16B slot, hash (row>>1)&3 == (l16>>1)&3.
    const int swz = (quad ^ ((l16 >> 1) & 3)) << 4;
    int aoff[4], boff[4];
#pragma unroll
    for (int i = 0; i < 4; ++i) {
        aoff[i] = (wm + i * 16 + l16) * 64 + swz;
        boff[i] = 8192 + (wn + i * 16 + l16) * 64 + swz;
    }

    // staging: one round = 256 thr x 16B = 4KB = 64 rows of 64B; wave w covers 16 rows.
    const int srow = w * 16 + (lane >> 2);                       // row within 64-row group
    const int scl = (((lane & 3) ^ ((lane >> 3) & 3)) << 4);     // inverse-swizzled byte col
    const char* pA = (const char*)(A + (size_t)(bm + srow) * K) + scl;
    const char* pB = (const char*)(B + (size_t)(bn + srow) * K) + scl;
    const size_t rK = (size_t)K * 128;         // 64 rows * K elems * 2B
    const int ldw = w * 1024;

    const int NT = K >> 5;                     // BK=32 -> 64B per row per tile

    floatx4 acc[4][4];
#pragma unroll
    for (int i = 0; i < 4; ++i)
#pragma unroll
        for (int j = 0; j < 4; ++j) acc[i][j] = (floatx4)0.f;

    // prologue: tile0 -> buf0, tile1 -> buf1 (4 loads each)
#pragma unroll
    for (int tt = 0; tt < 2; ++tt) {
        char* lb = smem + tt * 16384;
        gl_lds16(pA + (size_t)tt * 64, lb + ldw);
        gl_lds16(pA + (size_t)tt * 64 + rK, lb + ldw + 4096);
        gl_lds16(pB + (size_t)tt * 64, lb + 8192 + ldw);
        gl_lds16(pB + (size_t)tt * 64 + rK, lb + 8192 + ldw + 4096);
    }
    asm volatile("s_waitcnt vmcnt(4)" ::: "memory");  // tile0 landed; tile1 (4) in flight
    __builtin_amdgcn_s_barrier();

    for (int tile = 0; tile < NT; ++tile) {
        char* cb = smem + (tile & 1) * 16384;
        const bool st = (tile + 2) < NT;
        const size_t gof = (size_t)(tile + 2) * 64;

        // read this tile's fragments into registers
        bf16x8 af[4], bfr[4];
#pragma unroll
        for (int i = 0; i < 4; ++i) af[i] = *(const bf16x8*)(cb + aoff[i]);
#pragma unroll
        for (int j = 0; j < 4; ++j) bfr[j] = *(const bf16x8*)(cb + boff[j]);
        asm volatile("s_waitcnt lgkmcnt(0)" ::: "memory");
        __builtin_amdgcn_sched_barrier(0);
        __builtin_amdgcn_s_barrier();          // all waves done reading cb -> safe to overwrite

        // stage tile+2 into cb (the buffer just consumed)
        if (st) {
            gl_lds16(pA + gof, cb + ldw);
            gl_lds16(pA + gof + rK, cb + ldw + 4096);
            gl_lds16(pB + gof, cb + 8192 + ldw);
            gl_lds16(pB + gof + rK, cb + 8192 + ldw + 4096);
        }

        __builtin_amdgcn_s_setprio(1);
#pragma unroll
        for (int i = 0; i < 4; ++i)
#pragma unroll
            for (int j = 0; j < 4; ++j)
                acc[i][j] = __builtin_amdgcn_mfma_f32_16x16x32_bf16(af[i], bfr[j], acc[i][j], 0, 0, 0);
        __builtin_amdgcn_s_setprio(0);

        // boundary: tile+1 fully landed; tile+2's 4 loads stay in flight
        if (st) asm volatile("s_waitcnt vmcnt(4)" ::: "memory");
        else    asm volatile("s_waitcnt vmcnt(0)" ::: "memory");
        __builtin_amdgcn_s_barrier();
    }

    // epilogue
#pragma unroll
    for (int j = 0; j < 4; ++j) {
        const int n = bn + wn + j * 16 + l16;
        const float bv = BIASRELU ? bias[n] : 0.f;
#pragma unroll
        for (int i = 0; i < 4; ++i) {
            const int m = bm + wm + i * 16 + quad * 4;
#pragma unroll
            for (int r = 0; r < 4; ++r) {
                float v = acc[i][j][r] + bv;
                if (BIASRELU) v = fmaxf(v, 0.f);
                C[(size_t)(m + r) * N + n] = (bf16_t)v;
            }
        }
    }
}

// ---------------- RoPE in-place on fused bf16 qkv [L][3072] ----------------
__global__ __launch_bounds__(256) void rope_kernel(bf16_t* __restrict__ qkv) {
    int gid = blockIdx.x * 256 + threadIdx.x;  // L*NH*32
    int j = gid & 31;
    int hh = (gid >> 5) & 15;
    int l = gid >> 9;
    float freq = powf(10000.f, -(float)(2 * j) * (1.f / 64.f));
    float ang = (float)l * freq;
    float s = sinf(ang), c = cosf(ang);
    size_t base = (size_t)l * 3072 + hh * HD + j;
    float q1 = (float)qkv[base], q2 = (float)qkv[base + 32];
    qkv[base] = (bf16_t)(q1 * c - q2 * s);
    qkv[base + 32] = (bf16_t)(q2 * c + q1 * s);
    size_t kb = base + 1024;
    float k1 = (float)qkv[kb], k2 = (float)qkv[kb + 32];
    qkv[kb] = (bf16_t)(k1 * c - k2 * s);
    qkv[kb + 32] = (bf16_t)(k2 * c + k1 * s);
}

// ---------------- V transpose: qkvb v-part [token][h*64+d] -> vt[h][d][token] ----------------
__global__ __launch_bounds__(256) void v_transpose(const bf16_t* __restrict__ qkvb,
                                                   bf16_t* __restrict__ vt) {
    __shared__ bf16_t Ts[64 * 72];
    const int h = blockIdx.x;
    const int tt = blockIdx.y;
    const int t = threadIdx.x;
#pragma unroll
    for (int i = 0; i < 2; ++i) {
        int idx = t + i * 256;
        int row = idx >> 3, dg = idx & 7;
        *(bf16x8*)(Ts + row * 72 + dg * 8) =
            *(const bf16x8*)(qkvb + (size_t)(tt * 64 + row) * 3072 + 2048 + h * 64 + dg * 8);
    }
    __syncthreads();
#pragma unroll
    for (int i = 0; i < 2; ++i) {
        int idx = t + i * 256;
        int d = idx >> 3, tg = idx & 7;
        bf16x8 v;
#pragma unroll
        for (int s = 0; s < 8; ++s) v[s] = Ts[(tg * 8 + s) * 72 + d];
        *(bf16x8*)(vt + ((size_t)h * 64 + d) * 2048 + tt * 64 + tg * 8) = v;
    }
}

// ---------------- MFMA flash attention (bf16 in/out, fp32 softmax) ----------------
__global__ __launch_bounds__(256) void attn_mfma(const bf16_t* __restrict__ qkvb,
                                                 const bf16_t* __restrict__ vt,
                                                 bf16_t* __restrict__ o) {
    __shared__ alignas(16) bf16_t Qs[64 * 72];
    __shared__ alignas(16) bf16_t Ks[64 * 72];
    __shared__ alignas(16) bf16_t Vs[64 * 72];   // [dim][key]
    __shared__ alignas(16) bf16_t Ps[4][16 * 72];
    const int t = threadIdx.x;
    const int wave = t >> 6;
    const int lane = t & 63;
    const int quad = lane >> 4;
    const int l16 = lane & 15;
    const int h = blockIdx.x;
    const int y = blockIdx.y;
    const int qt = (y < 16) ? (31 - y) : (y - 16);   // heavy/light pairing per CU
    const int l0 = qt * 64;

#pragma unroll
    for (int i = 0; i < 2; ++i) {
        int idx = t + i * 256;
        int row = idx >> 3, dg = idx & 7;
        *(bf16x8*)(Qs + row * 72 + dg * 8) =
            *(const bf16x8*)(qkvb + (size_t)(l0 + row) * 3072 + h * HD + dg * 8);
    }

    float m_r[4], l_r[4];
    floatx4 acc_o[4];
#pragma unroll
    for (int r = 0; r < 4; ++r) { m_r[r] = -1e30f; l_r[r] = 0.f; }
#pragma unroll
    for (int n = 0; n < 4; ++n) acc_o[n] = (floatx4)0.f;

    for (int jt = 0; jt <= qt; ++jt) {
        const int j0 = jt * 64;
        __syncthreads();
#pragma unroll
        for (int i = 0; i < 2; ++i) {
            int idx = t + i * 256;
            int row = idx >> 3, dg = idx & 7;
            *(bf16x8*)(Ks + row * 72 + dg * 8) =
                *(const bf16x8*)(qkvb + (size_t)(j0 + row) * 3072 + 1024 + h * HD + dg * 8);
            *(bf16x8*)(Vs + row * 72 + dg * 8) =
                *(const bf16x8*)(vt + ((size_t)h * HD + row) * 2048 + j0 + dg * 8);
        }
        __syncthreads();

        // S = Q K^T : wave's 16 q-rows x 64 keys
        bf16x8 aq0 = *(const bf16x8*)(Qs + (wave * 16 + l16) * 72 + quad * 8);
        bf16x8 aq1 = *(const bf16x8*)(Qs + (wave * 16 + l16) * 72 + 32 + quad * 8);
        floatx4 sacc[4];
#pragma unroll
        for (int j = 0; j < 4; ++j) {
            bf16x8 bk0 = *(const bf16x8*)(Ks + (j * 16 + l16) * 72 + quad * 8);
            bf16x8 bk1 = *(const bf16x8*)(Ks + (j * 16 + l16) * 72 + 32 + quad * 8);
            floatx4 s = (floatx4)0.f;
            s = __builtin_amdgcn_mfma_f32_16x16x32_bf16(aq0, bk0, s, 0, 0, 0);
            s = __builtin_amdgcn_mfma_f32_16x16x32_bf16(aq1, bk1, s, 0, 0, 0);
            sacc[j] = s;
        }

        const bool diag = (jt == qt);
        float mt[4];
#pragma unroll
        for (int r = 0; r < 4; ++r) mt[r] = -1e30f;
#pragma unroll
        for (int j = 0; j < 4; ++j)
#pragma unroll
            for (int r = 0; r < 4; ++r) {
                float sv = sacc[j][r] * 0.125f;
                if (diag && (j * 16 + l16) > (wave * 16 + quad * 4 + r)) sv = -1e30f;
                sacc[j][r] = sv;
                mt[r] = fmaxf(mt[r], sv);
            }
#pragma unroll
        for (int r = 0; r < 4; ++r) {
            mt[r] = fmaxf(mt[r], __shfl_xor(mt[r], 1, 64));
            mt[r] = fmaxf(mt[r], __shfl_xor(mt[r], 2, 64));
            mt[r] = fmaxf(mt[r], __shfl_xor(mt[r], 4, 64));
            mt[r] = fmaxf(mt[r], __shfl_xor(mt[r], 8, 64));
        }
        float alpha[4], rs[4];
#pragma unroll
        for (int r = 0; r < 4; ++r) {
            float mn = fmaxf(m_r[r], mt[r]);
            alpha[r] = __expf(m_r[r] - mn);
            m_r[r] = mn;
            rs[r] = 0.f;
        }
#pragma unroll
        for (int j = 0; j < 4; ++j)
#pragma unroll
            for (int r = 0; r < 4; ++r) {
                float p = __expf(sacc[j][r] - m_r[r]);
                sacc[j][r] = p;
                rs[r] += p;
            }
#pragma unroll
        for (int r = 0; r < 4; ++r) {
            rs[r] += __shfl_xor(rs[r], 1, 64);
            rs[r] += __shfl_xor(rs[r], 2, 64);
            rs[r] += __shfl_xor(rs[r], 4, 64);
            rs[r] += __shfl_xor(rs[r], 8, 64);
            l_r[r] = l_r[r] * alpha[r] + rs[r];
        }
#pragma unroll
        for (int n = 0; n < 4; ++n)
#pragma unroll
            for (int r = 0; r < 4; ++r) acc_o[n][r] *= alpha[r];

        bf16_t* pw = Ps[wave];
#pragma unroll
        for (int j = 0; j < 4; ++j)
#pragma unroll
            for (int r = 0; r < 4; ++r)
                pw[(quad * 4 + r) * 72 + j * 16 + l16] = (bf16_t)sacc[j][r];

        bf16x8 ap0 = *(const bf16x8*)(pw + l16 * 72 + quad * 8);
        bf16x8 ap1 = *(const bf16x8*)(pw + l16 * 72 + 32 + quad * 8);
#pragma unroll
        for (int n = 0; n < 4; ++n) {
            bf16x8 bv0 = *(const bf16x8*)(Vs + (n * 16 + l16) * 72 + quad * 8);
            bf16x8 bv1 = *(const bf16x8*)(Vs + (n * 16 + l16) * 72 + 32 + quad * 8);
            acc_o[n] = __builtin_amdgcn_mfma_f32_16x16x32_bf16(ap0, bv0, acc_o[n], 0, 0, 0);
            acc_o[n] = __builtin_amdgcn_mfma_f32_16x16x32_bf16(ap1, bv1, acc_o[n], 0, 0, 0);
        }
    }

#pragma unroll
    for (int r = 0; r < 4; ++r) {
        float inv = 1.f / l_r[r];
        int row = l0 + wave * 16 + quad * 4 + r;
#pragma unroll
        for (int n = 0; n < 4; ++n)
            o[(size_t)row * DM + h * HD + n * 16 + l16] = (bf16_t)(acc_o[n][r] * inv);
    }
}

// ---------------- conv_out: h[L,DM] fp32 -> out[4, L] ----------------
__global__ __launch_bounds__(256) void conv_out_kernel(const float* __restrict__ h,
                                                       const float* __restrict__ w,
                                                       const float* __restrict__ b,
                                                       float* __restrict__ out) {
    int c = blockIdx.x >> 11;
    int l = blockIdx.x & 2047;
    int t = threadIdx.x;
    float acc = 0.f;
    const float* wc = w + c * (DM * 7);
    for (int idx = t; idx < DM * 7; idx += 256) {
        int d = idx / 7;
        int kk = idx - d * 7;
        int tt = l + kk - 6;
        if (tt >= 0) acc = fmaf(h[(size_t)tt * DM + d], wc[idx], acc);
    }
#pragma unroll
    for (int off = 1; off < 64; off <<= 1) acc += __shfl_xor(acc, off, 64);
    __shared__ float red[4];
    if ((t & 63) == 0) red[t >> 6] = acc;
    __syncthreads();
    if (t == 0) out[blockIdx.x] = red[0] + red[1] + red[2] + red[3] + b[c];
}

extern "C" void kernel_launch(void* const* d_in, const int* in_sizes, int n_in,
                              void* d_out, int out_size, void* d_ws, size_t ws_size,
                              hipStream_t stream) {
    const float* x = (const float*)d_in[0];
    const float* conv_in_w = (const float*)d_in[1];
    const float* conv_in_b = (const float*)d_in[2];
    const float* ln1_w = (const float*)d_in[3];
    const float* ln1_b = (const float*)d_in[4];
    const float* wq = (const float*)d_in[5];
    const float* wk = (const float*)d_in[6];
    const float* wv = (const float*)d_in[7];
    const float* wo = (const float*)d_in[8];
    const float* ln2_w = (const float*)d_in[9];
    const float* ln2_b = (const float*)d_in[10];
    const float* w1 = (const float*)d_in[11];
    const float* b1 = (const float*)d_in[12];
    const float* w2 = (const float*)d_in[13];
    const float* b2 = (const float*)d_in[14];
    const float* w3 = (const float*)d_in[15];
    const float* b3 = (const float*)d_in[16];
    const float* conv_out_w = (const float*)d_in[17];
    const float* conv_out_b = (const float*)d_in[18];

    char* W = (char*)d_ws;
    float* h = (float*)(W);                                  // 8 MB
    bf16_t* qkvb = (bf16_t*)(W + (8ull << 20));              // 12 MB [2048][3072] bf16
    bf16_t* hn = (bf16_t*)(W + (20ull << 20));               // 4 MB
    bf16_t* ob = (bf16_t*)(W + (24ull << 20));               // 4 MB
    bf16_t* f1 = (bf16_t*)(W + (28ull << 20));               // 16 MB
    bf16_t* f2 = (bf16_t*)(W + (44ull << 20));               // 16 MB
    bf16_t* vtb = (bf16_t*)(W + (60ull << 20));              // 4 MB [16][64][2048] bf16
    bf16_t* qkvw = (bf16_t*)(W + (64ull << 20));             // 24 MB
    bf16_t* wob = (bf16_t*)(W + (88ull << 20));              // 8 MB
    bf16_t* w1b = (bf16_t*)(W + (96ull << 20));              // 32 MB
    bf16_t* w2b = (bf16_t*)(W + (128ull << 20));             // 128 MB
    bf16_t* w3b = (bf16_t*)(W + (256ull << 20));             // 32 MB (end 288 MB)

    cvt_qkvw<<<12288, 256, 0, stream>>>(wq, wk, wv, qkvw);
    cvt_bf16<<<4096, 256, 0, stream>>>(wo, wob, 1048576);
    cvt_bf16<<<16384, 256, 0, stream>>>(w1, w1b, 4194304);
    cvt_bf16<<<65536, 256, 0, stream>>>(w2, w2b, 16777216);
    cvt_bf16<<<16384, 256, 0, stream>>>(w3, w3b, 4194304);

    conv_in_kernel<<<(L_SEQ * DM) / 256, 256, 0, stream>>>(x, conv_in_w, conv_in_b, h);

    for (int layer = 0; layer < 4; ++layer) {
        const float* ln1w = ln1_w + layer * DM;
        const float* ln1b = ln1_b + layer * DM;
        const float* ln2w = ln2_w + layer * DM;
        const float* ln2b = ln2_b + layer * DM;
        const bf16_t* qkvw_l = qkvw + (size_t)layer * 3072 * 1024;
        const bf16_t* wob_l = wob + (size_t)layer * DM * DM;
        const bf16_t* w1b_l = w1b + (size_t)layer * DFF * DM;
        const bf16_t* w2b_l = w2b + (size_t)layer * DFF * DFF;
        const bf16_t* w3b_l = w3b + (size_t)layer * DM * DFF;
        const float* b1_l = b1 + (size_t)layer * DFF;
        const float* b2_l = b2 + (size_t)layer * DFF;
        const float* b3_l = b3 + (size_t)layer * DM;

        rmsnorm_kernel<<<L_SEQ, 256, 0, stream>>>(h, ln1w, ln1b, hn);
        gemm_pl<false><<<dim3(3072 / 128, L_SEQ / 128), 256, 0, stream>>>(
            hn, qkvw_l, nullptr, qkvb, L_SEQ, 3072, 1024);
        rope_kernel<<<(L_SEQ * NH * 32) / 256, 256, 0, stream>>>(qkvb);
        v_transpose<<<dim3(NH, L_SEQ / 64), 256, 0, stream>>>(qkvb, vtb);
        attn_mfma<<<dim3(NH, L_SEQ / 64), 256, 0, stream>>>(qkvb, vtb, ob);
        gemm_bt<64, false, false, true, false><<<dim3(DM / 64, L_SEQ / 128), 256, 0, stream>>>(
            ob, wob_l, nullptr, h, h, L_SEQ, DM, DM);
        rmsnorm_kernel<<<L_SEQ, 256, 0, stream>>>(h, ln2w, ln2b, hn);
        gemm_pl<true><<<dim3(DFF / 128, L_SEQ / 128), 256, 0, stream>>>(
            hn, w1b_l, b1_l, f1, L_SEQ, DFF, 1024);
        gemm_pl<true><<<dim3(DFF / 128, L_SEQ / 128), 256, 0, stream>>>(
            f1, w2b_l, b2_l, f2, L_SEQ, DFF, DFF);
        gemm_bt<64, true, false, true, false><<<dim3(DM / 64, L_SEQ / 128), 256, 0, stream>>>(
            f2, w3b_l, b3_l, h, h, L_SEQ, DM, DFF);
    }

    conv_out_kernel<<<4 * L_SEQ, 256, 0, stream>>>(h, conv_out_w, conv_out_b, (float*)d_out);
}

// Round 5
// 1959.845 us; speedup vs baseline: 1.1109x; 1.0097x over previous
//
#include <hip/hip_runtime.h>
#include <math.h>

#define L_SEQ 2048
#define DM 1024
#define DFF 4096
#define NH 16
#define HD 64

typedef __bf16 bf16_t;
typedef __bf16 bf16x4 __attribute__((ext_vector_type(4)));
typedef __bf16 bf16x8 __attribute__((ext_vector_type(8)));
typedef float floatx4 __attribute__((ext_vector_type(4)));

__device__ __forceinline__ void gl_lds16(const void* g, void* l) {
    __builtin_amdgcn_global_load_lds((const __attribute__((address_space(1))) void*)g,
                                     (__attribute__((address_space(3))) void*)l, 16, 0, 0);
}

// ---------------- conv_in + relu + transpose: x[4,L] -> h[L, DM] fp32 ----------------
__global__ __launch_bounds__(256) void conv_in_kernel(const float* __restrict__ x,
                                                      const float* __restrict__ w,
                                                      const float* __restrict__ b,
                                                      float* __restrict__ h) {
    int gid = blockIdx.x * 256 + threadIdx.x;
    int d = gid & (DM - 1);
    int l = gid >> 10;
    float acc = b[d];
    const float* wd = w + d * 28;
#pragma unroll
    for (int c = 0; c < 4; ++c) {
#pragma unroll
        for (int k = 0; k < 7; ++k) {
            int t = l + k - 6;
            float xv = (t >= 0) ? x[c * L_SEQ + t] : 0.f;
            acc = fmaf(xv, wd[c * 7 + k], acc);
        }
    }
    h[(size_t)l * DM + d] = fmaxf(acc, 0.f);
}

// ---------------- RMSNorm fp32 in -> bf16 out ----------------
__global__ __launch_bounds__(256) void rmsnorm_kernel(const float* __restrict__ h,
                                                      const float* __restrict__ w,
                                                      const float* __restrict__ b,
                                                      bf16_t* __restrict__ out) {
    int l = blockIdx.x;
    int t = threadIdx.x;
    const float* row = h + (size_t)l * DM;
    float4 xv = *(const float4*)(row + t * 4);
    float ss = xv.x * xv.x + xv.y * xv.y + xv.z * xv.z + xv.w * xv.w;
#pragma unroll
    for (int off = 1; off < 64; off <<= 1) ss += __shfl_xor(ss, off, 64);
    __shared__ float red[4];
    if ((t & 63) == 0) red[t >> 6] = ss;
    __syncthreads();
    float tot = red[0] + red[1] + red[2] + red[3];
    float inv = rsqrtf(tot * (1.f / DM) + 1e-5f);
    float4 wv = *(const float4*)(w + t * 4);
    float4 bv = *(const float4*)(b + t * 4);
    bf16x4 ov;
    ov.x = (bf16_t)fmaf(xv.x * inv, wv.x, bv.x);
    ov.y = (bf16_t)fmaf(xv.y * inv, wv.y, bv.y);
    ov.z = (bf16_t)fmaf(xv.z * inv, wv.z, bv.z);
    ov.w = (bf16_t)fmaf(xv.w * inv, wv.w, bv.w);
    *(bf16x4*)(out + (size_t)l * DM + t * 4) = ov;
}

// ---------------- weight conversion fp32 -> bf16 ----------------
__global__ __launch_bounds__(256) void cvt_bf16(const float* __restrict__ in,
                                                bf16_t* __restrict__ out, int n4) {
    int i = blockIdx.x * 256 + threadIdx.x;
    if (i < n4) {
        float4 v = *(const float4*)(in + (size_t)i * 4);
        bf16x4 o = {(bf16_t)v.x, (bf16_t)v.y, (bf16_t)v.z, (bf16_t)v.w};
        *(bf16x4*)(out + (size_t)i * 4) = o;
    }
}

// wq/wk/wv [4][1024][1024] fp32 -> fused [4][3072][1024] bf16
__global__ __launch_bounds__(256) void cvt_qkvw(const float* __restrict__ wq,
                                                const float* __restrict__ wk,
                                                const float* __restrict__ wv,
                                                bf16_t* __restrict__ out) {
    int i = blockIdx.x * 256 + threadIdx.x;
    int layer = i / 786432;
    int rem = i - layer * 786432;
    int sel = rem / 262144;
    int idx = rem - sel * 262144;
    const float* src = (sel == 0 ? wq : sel == 1 ? wk : wv) + (size_t)layer * 1048576 + (size_t)idx * 4;
    float4 v = *(const float4*)src;
    bf16x4 o = {(bf16_t)v.x, (bf16_t)v.y, (bf16_t)v.z, (bf16_t)v.w};
    *(bf16x4*)(out + (size_t)i * 4) = o;
}

// ---------------- pipelined bf16 MFMA GEMM NT: 128x128 tile, BK=32, 32KB LDS ----------------
// 4 waves (2M x 2N), per-wave 64x64. Double-buffered LDS (2 x 16KB), 2-deep prefetch,
// counted vmcnt(4) at the tile boundary (never drains in steady state).
// Bank-swizzle: 64B rows, 16B slot q of row r at phys slot q ^ ((r>>1)&3), applied as
// inverse-swizzled global source (global_load_lds writes linearly) + swizzled ds_read.
// Epilogue template flags: BIAS (+bias[n]), RELU, RES (+res fp32), OUTBF (bf16 vs f32 out).
template <bool BIAS, bool RELU, bool RES, bool OUTBF>
__global__ __launch_bounds__(256, 2) void gemm_pl(const bf16_t* __restrict__ A,
                                                  const bf16_t* __restrict__ B,
                                                  const float* __restrict__ bias,
                                                  const float* __restrict__ res,
                                                  void* __restrict__ Cout,
                                                  int M, int N, int K) {
    __shared__ alignas(16) char smem[32768];   // 2 x (A 8KB + B 8KB)
    const int t = threadIdx.x;
    const int w = t >> 6;
    const int lane = t & 63;
    const int quad = lane >> 4;
    const int l16 = lane & 15;
    const int bm = blockIdx.y * 128;
    const int bn = blockIdx.x * 128;
    const int wm = (w >> 1) * 64;   // 2 M-groups
    const int wn = (w & 1) * 64;    // 2 N-groups

    // ds_read offsets: row*64B + swizzled 16B slot, hash (row>>1)&3 == (l16>>1)&3.
    const int swz = (quad ^ ((l16 >> 1) & 3)) << 4;
    int aoff[4], boff[4];
#pragma unroll
    for (int i = 0; i < 4; ++i) {
        aoff[i] = (wm + i * 16 + l16) * 64 + swz;
        boff[i] = 8192 + (wn + i * 16 + l16) * 64 + swz;
    }

    // staging: one round = 256 thr x 16B = 4KB = 64 rows of 64B; wave w covers 16 rows.
    const int srow = w * 16 + (lane >> 2);                       // row within 64-row group
    const int scl = (((lane & 3) ^ ((lane >> 3) & 3)) << 4);     // inverse-swizzled byte col
    const char* pA = (const char*)(A + (size_t)(bm + srow) * K) + scl;
    const char* pB = (const char*)(B + (size_t)(bn + srow) * K) + scl;
    const size_t rK = (size_t)K * 128;         // 64 rows * K elems * 2B
    const int ldw = w * 1024;

    const int NT = K >> 5;                     // BK=32 -> 64B per row per tile

    floatx4 acc[4][4];
#pragma unroll
    for (int i = 0; i < 4; ++i)
#pragma unroll
        for (int j = 0; j < 4; ++j) acc[i][j] = (floatx4)0.f;

    // prologue: tile0 -> buf0, tile1 -> buf1 (4 loads each)
#pragma unroll
    for (int tt = 0; tt < 2; ++tt) {
        char* lb = smem + tt * 16384;
        gl_lds16(pA + (size_t)tt * 64, lb + ldw);
        gl_lds16(pA + (size_t)tt * 64 + rK, lb + ldw + 4096);
        gl_lds16(pB + (size_t)tt * 64, lb + 8192 + ldw);
        gl_lds16(pB + (size_t)tt * 64 + rK, lb + 8192 + ldw + 4096);
    }
    asm volatile("s_waitcnt vmcnt(4)" ::: "memory");  // tile0 landed; tile1 (4) in flight
    __builtin_amdgcn_s_barrier();

    for (int tile = 0; tile < NT; ++tile) {
        char* cb = smem + (tile & 1) * 16384;
        const bool st = (tile + 2) < NT;
        const size_t gof = (size_t)(tile + 2) * 64;

        // read this tile's fragments into registers
        bf16x8 af[4], bfr[4];
#pragma unroll
        for (int i = 0; i < 4; ++i) af[i] = *(const bf16x8*)(cb + aoff[i]);
#pragma unroll
        for (int j = 0; j < 4; ++j) bfr[j] = *(const bf16x8*)(cb + boff[j]);
        asm volatile("s_waitcnt lgkmcnt(0)" ::: "memory");
        __builtin_amdgcn_sched_barrier(0);
        __builtin_amdgcn_s_barrier();          // all waves done reading cb -> safe to overwrite

        // stage tile+2 into cb (the buffer just consumed)
        if (st) {
            gl_lds16(pA + gof, cb + ldw);
            gl_lds16(pA + gof + rK, cb + ldw + 4096);
            gl_lds16(pB + gof, cb + 8192 + ldw);
            gl_lds16(pB + gof + rK, cb + 8192 + ldw + 4096);
        }

        __builtin_amdgcn_s_setprio(1);
#pragma unroll
        for (int i = 0; i < 4; ++i)
#pragma unroll
            for (int j = 0; j < 4; ++j)
                acc[i][j] = __builtin_amdgcn_mfma_f32_16x16x32_bf16(af[i], bfr[j], acc[i][j], 0, 0, 0);
        __builtin_amdgcn_s_setprio(0);

        // boundary: tile+1 fully landed; tile+2's 4 loads stay in flight
        if (st) asm volatile("s_waitcnt vmcnt(4)" ::: "memory");
        else    asm volatile("s_waitcnt vmcnt(0)" ::: "memory");
        __builtin_amdgcn_s_barrier();
    }

    // epilogue
#pragma unroll
    for (int j = 0; j < 4; ++j) {
        const int n = bn + wn + j * 16 + l16;
        const float bv = BIAS ? bias[n] : 0.f;
#pragma unroll
        for (int i = 0; i < 4; ++i) {
            const int m = bm + wm + i * 16 + quad * 4;
#pragma unroll
            for (int r = 0; r < 4; ++r) {
                float v = acc[i][j][r] + bv;
                if (RELU) v = fmaxf(v, 0.f);
                if (RES) v += res[(size_t)(m + r) * N + n];
                if (OUTBF) ((bf16_t*)Cout)[(size_t)(m + r) * N + n] = (bf16_t)v;
                else ((float*)Cout)[(size_t)(m + r) * N + n] = v;
            }
        }
    }
}

// ---------------- RoPE in-place on fused bf16 qkv [L][3072] ----------------
__global__ __launch_bounds__(256) void rope_kernel(bf16_t* __restrict__ qkv) {
    int gid = blockIdx.x * 256 + threadIdx.x;  // L*NH*32
    int j = gid & 31;
    int hh = (gid >> 5) & 15;
    int l = gid >> 9;
    float freq = powf(10000.f, -(float)(2 * j) * (1.f / 64.f));
    float ang = (float)l * freq;
    float s = sinf(ang), c = cosf(ang);
    size_t base = (size_t)l * 3072 + hh * HD + j;
    float q1 = (float)qkv[base], q2 = (float)qkv[base + 32];
    qkv[base] = (bf16_t)(q1 * c - q2 * s);
    qkv[base + 32] = (bf16_t)(q2 * c + q1 * s);
    size_t kb = base + 1024;
    float k1 = (float)qkv[kb], k2 = (float)qkv[kb + 32];
    qkv[kb] = (bf16_t)(k1 * c - k2 * s);
    qkv[kb + 32] = (bf16_t)(k2 * c + k1 * s);
}

// ---------------- V transpose: qkvb v-part [token][h*64+d] -> vt[h][d][token] ----------------
__global__ __launch_bounds__(256) void v_transpose(const bf16_t* __restrict__ qkvb,
                                                   bf16_t* __restrict__ vt) {
    __shared__ bf16_t Ts[64 * 72];
    const int h = blockIdx.x;
    const int tt = blockIdx.y;
    const int t = threadIdx.x;
#pragma unroll
    for (int i = 0; i < 2; ++i) {
        int idx = t + i * 256;
        int row = idx >> 3, dg = idx & 7;
        *(bf16x8*)(Ts + row * 72 + dg * 8) =
            *(const bf16x8*)(qkvb + (size_t)(tt * 64 + row) * 3072 + 2048 + h * 64 + dg * 8);
    }
    __syncthreads();
#pragma unroll
    for (int i = 0; i < 2; ++i) {
        int idx = t + i * 256;
        int d = idx >> 3, tg = idx & 7;
        bf16x8 v;
#pragma unroll
        for (int s = 0; s < 8; ++s) v[s] = Ts[(tg * 8 + s) * 72 + d];
        *(bf16x8*)(vt + ((size_t)h * 64 + d) * 2048 + tt * 64 + tg * 8) = v;
    }
}

// ---------------- MFMA flash attention (bf16 in/out, fp32 softmax) ----------------
__global__ __launch_bounds__(256) void attn_mfma(const bf16_t* __restrict__ qkvb,
                                                 const bf16_t* __restrict__ vt,
                                                 bf16_t* __restrict__ o) {
    __shared__ alignas(16) bf16_t Qs[64 * 72];
    __shared__ alignas(16) bf16_t Ks[64 * 72];
    __shared__ alignas(16) bf16_t Vs[64 * 72];   // [dim][key]
    __shared__ alignas(16) bf16_t Ps[4][16 * 72];
    const int t = threadIdx.x;
    const int wave = t >> 6;
    const int lane = t & 63;
    const int quad = lane >> 4;
    const int l16 = lane & 15;
    const int h = blockIdx.x;
    const int y = blockIdx.y;
    const int qt = (y < 16) ? (31 - y) : (y - 16);   // heavy/light pairing per CU
    const int l0 = qt * 64;

#pragma unroll
    for (int i = 0; i < 2; ++i) {
        int idx = t + i * 256;
        int row = idx >> 3, dg = idx & 7;
        *(bf16x8*)(Qs + row * 72 + dg * 8) =
            *(const bf16x8*)(qkvb + (size_t)(l0 + row) * 3072 + h * HD + dg * 8);
    }

    float m_r[4], l_r[4];
    floatx4 acc_o[4];
#pragma unroll
    for (int r = 0; r < 4; ++r) { m_r[r] = -1e30f; l_r[r] = 0.f; }
#pragma unroll
    for (int n = 0; n < 4; ++n) acc_o[n] = (floatx4)0.f;

    for (int jt = 0; jt <= qt; ++jt) {
        const int j0 = jt * 64;
        __syncthreads();
#pragma unroll
        for (int i = 0; i < 2; ++i) {
            int idx = t + i * 256;
            int row = idx >> 3, dg = idx & 7;
            *(bf16x8*)(Ks + row * 72 + dg * 8) =
                *(const bf16x8*)(qkvb + (size_t)(j0 + row) * 3072 + 1024 + h * HD + dg * 8);
            *(bf16x8*)(Vs + row * 72 + dg * 8) =
                *(const bf16x8*)(vt + ((size_t)h * HD + row) * 2048 + j0 + dg * 8);
        }
        __syncthreads();

        // S = Q K^T : wave's 16 q-rows x 64 keys
        bf16x8 aq0 = *(const bf16x8*)(Qs + (wave * 16 + l16) * 72 + quad * 8);
        bf16x8 aq1 = *(const bf16x8*)(Qs + (wave * 16 + l16) * 72 + 32 + quad * 8);
        floatx4 sacc[4];
#pragma unroll
        for (int j = 0; j < 4; ++j) {
            bf16x8 bk0 = *(const bf16x8*)(Ks + (j * 16 + l16) * 72 + quad * 8);
            bf16x8 bk1 = *(const bf16x8*)(Ks + (j * 16 + l16) * 72 + 32 + quad * 8);
            floatx4 s = (floatx4)0.f;
            s = __builtin_amdgcn_mfma_f32_16x16x32_bf16(aq0, bk0, s, 0, 0, 0);
            s = __builtin_amdgcn_mfma_f32_16x16x32_bf16(aq1, bk1, s, 0, 0, 0);
            sacc[j] = s;
        }

        const bool diag = (jt == qt);
        float mt[4];
#pragma unroll
        for (int r = 0; r < 4; ++r) mt[r] = -1e30f;
#pragma unroll
        for (int j = 0; j < 4; ++j)
#pragma unroll
            for (int r = 0; r < 4; ++r) {
                float sv = sacc[j][r] * 0.125f;
                if (diag && (j * 16 + l16) > (wave * 16 + quad * 4 + r)) sv = -1e30f;
                sacc[j][r] = sv;
                mt[r] = fmaxf(mt[r], sv);
            }
#pragma unroll
        for (int r = 0; r < 4; ++r) {
            mt[r] = fmaxf(mt[r], __shfl_xor(mt[r], 1, 64));
            mt[r] = fmaxf(mt[r], __shfl_xor(mt[r], 2, 64));
            mt[r] = fmaxf(mt[r], __shfl_xor(mt[r], 4, 64));
            mt[r] = fmaxf(mt[r], __shfl_xor(mt[r], 8, 64));
        }
        float alpha[4], rs[4];
#pragma unroll
        for (int r = 0; r < 4; ++r) {
            float mn = fmaxf(m_r[r], mt[r]);
            alpha[r] = __expf(m_r[r] - mn);
            m_r[r] = mn;
            rs[r] = 0.f;
        }
#pragma unroll
        for (int j = 0; j < 4; ++j)
#pragma unroll
            for (int r = 0; r < 4; ++r) {
                float p = __expf(sacc[j][r] - m_r[r]);
                sacc[j][r] = p;
                rs[r] += p;
            }
#pragma unroll
        for (int r = 0; r < 4; ++r) {
            rs[r] += __shfl_xor(rs[r], 1, 64);
            rs[r] += __shfl_xor(rs[r], 2, 64);
            rs[r] += __shfl_xor(rs[r], 4, 64);
            rs[r] += __shfl_xor(rs[r], 8, 64);
            l_r[r] = l_r[r] * alpha[r] + rs[r];
        }
#pragma unroll
        for (int n = 0; n < 4; ++n)
#pragma unroll
            for (int r = 0; r < 4; ++r) acc_o[n][r] *= alpha[r];

        bf16_t* pw = Ps[wave];
#pragma unroll
        for (int j = 0; j < 4; ++j)
#pragma unroll
            for (int r = 0; r < 4; ++r)
                pw[(quad * 4 + r) * 72 + j * 16 + l16] = (bf16_t)sacc[j][r];

        bf16x8 ap0 = *(const bf16x8*)(pw + l16 * 72 + quad * 8);
        bf16x8 ap1 = *(const bf16x8*)(pw + l16 * 72 + 32 + quad * 8);
#pragma unroll
        for (int n = 0; n < 4; ++n) {
            bf16x8 bv0 = *(const bf16x8*)(Vs + (n * 16 + l16) * 72 + quad * 8);
            bf16x8 bv1 = *(const bf16x8*)(Vs + (n * 16 + l16) * 72 + 32 + quad * 8);
            acc_o[n] = __builtin_amdgcn_mfma_f32_16x16x32_bf16(ap0, bv0, acc_o[n], 0, 0, 0);
            acc_o[n] = __builtin_amdgcn_mfma_f32_16x16x32_bf16(ap1, bv1, acc_o[n], 0, 0, 0);
        }
    }

#pragma unroll
    for (int r = 0; r < 4; ++r) {
        float inv = 1.f / l_r[r];
        int row = l0 + wave * 16 + quad * 4 + r;
#pragma unroll
        for (int n = 0; n < 4; ++n)
            o[(size_t)row * DM + h * HD + n * 16 + l16] = (bf16_t)(acc_o[n][r] * inv);
    }
}

// ---------------- conv_out: h[L,DM] fp32 -> out[4, L] ----------------
__global__ __launch_bounds__(256) void conv_out_kernel(const float* __restrict__ h,
                                                       const float* __restrict__ w,
                                                       const float* __restrict__ b,
                                                       float* __restrict__ out) {
    int c = blockIdx.x >> 11;
    int l = blockIdx.x & 2047;
    int t = threadIdx.x;
    float acc = 0.f;
    const float* wc = w + c * (DM * 7);
    for (int idx = t; idx < DM * 7; idx += 256) {
        int d = idx / 7;
        int kk = idx - d * 7;
        int tt = l + kk - 6;
        if (tt >= 0) acc = fmaf(h[(size_t)tt * DM + d], wc[idx], acc);
    }
#pragma unroll
    for (int off = 1; off < 64; off <<= 1) acc += __shfl_xor(acc, off, 64);
    __shared__ float red[4];
    if ((t & 63) == 0) red[t >> 6] = acc;
    __syncthreads();
    if (t == 0) out[blockIdx.x] = red[0] + red[1] + red[2] + red[3] + b[c];
}

extern "C" void kernel_launch(void* const* d_in, const int* in_sizes, int n_in,
                              void* d_out, int out_size, void* d_ws, size_t ws_size,
                              hipStream_t stream) {
    const float* x = (const float*)d_in[0];
    const float* conv_in_w = (const float*)d_in[1];
    const float* conv_in_b = (const float*)d_in[2];
    const float* ln1_w = (const float*)d_in[3];
    const float* ln1_b = (const float*)d_in[4];
    const float* wq = (const float*)d_in[5];
    const float* wk = (const float*)d_in[6];
    const float* wv = (const float*)d_in[7];
    const float* wo = (const float*)d_in[8];
    const float* ln2_w = (const float*)d_in[9];
    const float* ln2_b = (const float*)d_in[10];
    const float* w1 = (const float*)d_in[11];
    const float* b1 = (const float*)d_in[12];
    const float* w2 = (const float*)d_in[13];
    const float* b2 = (const float*)d_in[14];
    const float* w3 = (const float*)d_in[15];
    const float* b3 = (const float*)d_in[16];
    const float* conv_out_w = (const float*)d_in[17];
    const float* conv_out_b = (const float*)d_in[18];

    char* W = (char*)d_ws;
    float* h = (float*)(W);                                  // 8 MB
    bf16_t* qkvb = (bf16_t*)(W + (8ull << 20));              // 12 MB [2048][3072] bf16
    bf16_t* hn = (bf16_t*)(W + (20ull << 20));               // 4 MB
    bf16_t* ob = (bf16_t*)(W + (24ull << 20));               // 4 MB
    bf16_t* f1 = (bf16_t*)(W + (28ull << 20));               // 16 MB
    bf16_t* f2 = (bf16_t*)(W + (44ull << 20));               // 16 MB
    bf16_t* vtb = (bf16_t*)(W + (60ull << 20));              // 4 MB [16][64][2048] bf16
    bf16_t* qkvw = (bf16_t*)(W + (64ull << 20));             // 24 MB
    bf16_t* wob = (bf16_t*)(W + (88ull << 20));              // 8 MB
    bf16_t* w1b = (bf16_t*)(W + (96ull << 20));              // 32 MB
    bf16_t* w2b = (bf16_t*)(W + (128ull << 20));             // 128 MB
    bf16_t* w3b = (bf16_t*)(W + (256ull << 20));             // 32 MB (end 288 MB)

    cvt_qkvw<<<12288, 256, 0, stream>>>(wq, wk, wv, qkvw);
    cvt_bf16<<<4096, 256, 0, stream>>>(wo, wob, 1048576);
    cvt_bf16<<<16384, 256, 0, stream>>>(w1, w1b, 4194304);
    cvt_bf16<<<65536, 256, 0, stream>>>(w2, w2b, 16777216);
    cvt_bf16<<<16384, 256, 0, stream>>>(w3, w3b, 4194304);

    conv_in_kernel<<<(L_SEQ * DM) / 256, 256, 0, stream>>>(x, conv_in_w, conv_in_b, h);

    for (int layer = 0; layer < 4; ++layer) {
        const float* ln1w = ln1_w + layer * DM;
        const float* ln1b = ln1_b + layer * DM;
        const float* ln2w = ln2_w + layer * DM;
        const float* ln2b = ln2_b + layer * DM;
        const bf16_t* qkvw_l = qkvw + (size_t)layer * 3072 * 1024;
        const bf16_t* wob_l = wob + (size_t)layer * DM * DM;
        const bf16_t* w1b_l = w1b + (size_t)layer * DFF * DM;
        const bf16_t* w2b_l = w2b + (size_t)layer * DFF * DFF;
        const bf16_t* w3b_l = w3b + (size_t)layer * DM * DFF;
        const float* b1_l = b1 + (size_t)layer * DFF;
        const float* b2_l = b2 + (size_t)layer * DFF;
        const float* b3_l = b3 + (size_t)layer * DM;

        rmsnorm_kernel<<<L_SEQ, 256, 0, stream>>>(h, ln1w, ln1b, hn);
        gemm_pl<false, false, false, true><<<dim3(3072 / 128, L_SEQ / 128), 256, 0, stream>>>(
            hn, qkvw_l, nullptr, nullptr, qkvb, L_SEQ, 3072, 1024);
        rope_kernel<<<(L_SEQ * NH * 32) / 256, 256, 0, stream>>>(qkvb);
        v_transpose<<<dim3(NH, L_SEQ / 64), 256, 0, stream>>>(qkvb, vtb);
        attn_mfma<<<dim3(NH, L_SEQ / 64), 256, 0, stream>>>(qkvb, vtb, ob);
        gemm_pl<false, false, true, false><<<dim3(DM / 128, L_SEQ / 128), 256, 0, stream>>>(
            ob, wob_l, nullptr, h, h, L_SEQ, DM, DM);
        rmsnorm_kernel<<<L_SEQ, 256, 0, stream>>>(h, ln2w, ln2b, hn);
        gemm_pl<true, true, false, true><<<dim3(DFF / 128, L_SEQ / 128), 256, 0, stream>>>(
            hn, w1b_l, b1_l, nullptr, f1, L_SEQ, DFF, 1024);
        gemm_pl<true, true, false, true><<<dim3(DFF / 128, L_SEQ / 128), 256, 0, stream>>>(
            f1, w2b_l, b2_l, nullptr, f2, L_SEQ, DFF, DFF);
        gemm_pl<true, false, true, false><<<dim3(DM / 128, L_SEQ / 128), 256, 0, stream>>>(
            f2, w3b_l, b3_l, h, h, L_SEQ, DM, DFF);
    }

    conv_out_kernel<<<4 * L_SEQ, 256, 0, stream>>>(h, conv_out_w, conv_out_b, (float*)d_out);
}